// Round 9
// baseline (206.871 us; speedup 1.0000x reference)
//
#include <hip/hip_runtime.h>
#include <math.h>

#define NUM_Q_ 10000
#define NUM_A_ 10000
#define DIM 128
#define MSZ 50
#define BB 64
#define NN 200
#define SEG 8
#define SLEN 25
#define K1SEG 7

typedef float f4 __attribute__((ext_vector_type(4)));

__device__ __forceinline__ float hadd(f4 v) { return (v.x + v.y) + (v.z + v.w); }
// m -> slot in [25][56] padded w layout (halves at 0 and 28; 25 used + 3 zero pad)
__device__ __forceinline__ int wslot(int m) { return m + (m >= 25 ? 3 : 0); }

// ============ K1 (R7 kernA, proven): gather + GEMVs + softmax + affine aggregates ============
__global__ __launch_bounds__(256, 2) void kernA(
    const int* __restrict__ q, const int* __restrict__ r, const int* __restrict__ a,
    const float* __restrict__ Kemb, const float* __restrict__ Vemb, const float* __restrict__ VAemb,
    const float* __restrict__ Mk, const float* __restrict__ eW, const float* __restrict__ eb,
    const float* __restrict__ aW, const float* __restrict__ ab,
    float* __restrict__ w_ws, float* __restrict__ e_ws, float* __restrict__ ad_ws,
    float* __restrict__ Aseg, float* __restrict__ Bseg)
{
    __shared__ float s_s[SLEN * DIM];
    __shared__ float s_k[SLEN * DIM];
    __shared__ float w_s[SLEN * 56];
    __shared__ float e_s[SLEN * DIM];
    __shared__ float a_s[SLEN * DIM];
    __shared__ int   idxs[96];

    const int bid = blockIdx.x;
    const int b = bid & 63, seg = bid >> 6;
    const int t0 = seg * SLEN;
    const int tid = threadIdx.x;
    const int lane = tid & 63, wv = tid >> 6;

    if (tid < SLEN) {
        int pos = b * NN + t0 + tid;
        int qi = q[pos], ri = r[pos], ai = a[pos];
        idxs[tid]      = qi;
        idxs[32 + tid] = qi + NUM_Q_ * ri;
        idxs[64 + tid] = ai + NUM_A_ * ri;
    }
    for (int k = tid; k < SLEN * 56; k += 256) w_s[k] = 0.f;
    __syncthreads();

    for (int k = tid; k < SLEN * DIM; k += 256) {
        int pl = k >> 7, dc = k & 127;
        s_k[k] = Kemb[(size_t)idxs[pl] * DIM + dc];
        s_s[k] = Vemb[(size_t)idxs[32 + pl] * DIM + dc]
               + VAemb[(size_t)idxs[64 + pl] * DIM + dc];
    }
    __syncthreads();

    {
        const int pw0 = (wv == 0) ? 0 : 7 + 6 * (wv - 1);   // 0,7,13,19
        const int npw = (wv == 0) ? 7 : 6;
        f4 ac0[7], ac1[7], ac2[7], ac3[7], acl[7];
        #pragma unroll
        for (int p = 0; p < 7; ++p) {
            ac0[p] = f4{0,0,0,0}; ac1[p] = f4{0,0,0,0}; ac2[p] = f4{0,0,0,0};
            ac3[p] = f4{0,0,0,0}; acl[p] = f4{0,0,0,0};
        }
        const f4* W0 = (const f4*)(eW + (size_t)lane * DIM);
        const f4* W1 = (const f4*)(eW + (size_t)(lane + 64) * DIM);
        const f4* W2 = (const f4*)(aW + (size_t)lane * DIM);
        const f4* W3 = (const f4*)(aW + (size_t)(lane + 64) * DIM);
        const f4* WM = (const f4*)(Mk + (size_t)(lane < MSZ ? lane : 0) * DIM);

        for (int i4 = 0; i4 < 32; ++i4) {
            f4 w0 = W0[i4], w1 = W1[i4], w2 = W2[i4], w3 = W3[i4], wm = WM[i4];
            #pragma unroll
            for (int p = 0; p < 7; ++p) {
                if (p < npw) {
                    int pos = pw0 + p;
                    f4 s4 = *(const f4*)&s_s[pos * DIM + i4 * 4];
                    f4 k4 = *(const f4*)&s_k[pos * DIM + i4 * 4];
                    ac0[p] += w0 * s4;
                    ac1[p] += w1 * s4;
                    ac2[p] += w2 * s4;
                    ac3[p] += w3 * s4;
                    acl[p] += wm * k4;
                }
            }
        }
        const float eb0 = eb[lane], eb1 = eb[lane + 64];
        const float ab0 = ab[lane], ab1 = ab[lane + 64];
        #pragma unroll
        for (int p = 0; p < 7; ++p) {
            if (p < npw) {
                int pos = pw0 + p;
                size_t g = (size_t)(b * NN + t0 + pos) * DIM;
                float v0 = 1.f / (1.f + __expf(-(hadd(ac0[p]) + eb0)));
                float v1 = 1.f / (1.f + __expf(-(hadd(ac1[p]) + eb1)));
                float v2 = tanhf(hadd(ac2[p]) + ab0);
                float v3 = tanhf(hadd(ac3[p]) + ab1);
                e_s[pos * DIM + lane] = v0;        e_ws[g + lane] = v0;
                e_s[pos * DIM + lane + 64] = v1;   e_ws[g + lane + 64] = v1;
                a_s[pos * DIM + lane] = v2;        ad_ws[g + lane] = v2;
                a_s[pos * DIM + lane + 64] = v3;   ad_ws[g + lane + 64] = v3;
                if (lane < MSZ) w_s[pos * 56 + wslot(lane)] = hadd(acl[p]);
            }
        }
    }
    __syncthreads();

    if (tid < SLEN) {   // softmax over m
        float mx = -1e30f;
        #pragma unroll
        for (int m = 0; m < MSZ; ++m) mx = fmaxf(mx, w_s[tid * 56 + wslot(m)]);
        float sm = 0.f;
        float ex[MSZ];
        #pragma unroll
        for (int m = 0; m < MSZ; ++m) {
            ex[m] = __expf(w_s[tid * 56 + wslot(m)] - mx);
            sm += ex[m];
        }
        float inv = 1.f / sm;
        size_t g = (size_t)(b * NN + t0 + tid) * MSZ;
        #pragma unroll
        for (int m = 0; m < MSZ; ++m) {
            float wv2 = ex[m] * inv;
            w_s[tid * 56 + wslot(m)] = wv2;
            w_ws[g + m] = wv2;
        }
    }
    __syncthreads();

    if (seg < K1SEG) {  // per-segment affine aggregates
        const int d = tid & 127, mh = tid >> 7;
        float A[28], Bv[28];
        #pragma unroll
        for (int j = 0; j < 28; ++j) { A[j] = 1.f; Bv[j] = 0.f; }
        for (int tc = 0; tc < SLEN; ++tc) {
            float ev = e_s[tc * DIM + d], av = a_s[tc * DIM + d];
            #pragma unroll
            for (int g = 0; g < 7; ++g) {
                f4 w4 = *(const f4*)&w_s[tc * 56 + mh * 28 + g * 4];
                #pragma unroll
                for (int c = 0; c < 4; ++c) {
                    int j = g * 4 + c;
                    float wj = w4[c];                 // pads are 0 -> inert
                    float f = fmaf(-wj, ev, 1.f);
                    Bv[j] = fmaf(Bv[j], f, wj * av);
                    A[j] *= f;
                }
            }
        }
        size_t base = (size_t)(b * K1SEG + seg) * (MSZ * DIM) + (size_t)(mh * SLEN) * DIM + d;
        #pragma unroll
        for (int j = 0; j < SLEN; ++j) {
            Aseg[base + j * DIM] = A[j];
            Bseg[base + j * DIM] = Bv[j];
        }
    }
}

// ============ K2: prefix-combine + scan (wave-contiguous dwordx4 stream) + fused head ============
// 512 blocks (bid = seg*64 + b) x 256 thr, 3 blocks/CU. Wave wv owns row-pairs
// [p0,p0+np); thread: row = 2*(p0+j)+hl, cols d0..d0+3 -> 1KB contiguous per wave store.
__global__ __launch_bounds__(256, 3) void kernB(
    const int* __restrict__ q, const float* __restrict__ Kemb, const float* __restrict__ Mv0,
    const float* __restrict__ Aseg, const float* __restrict__ Bseg,
    const float* __restrict__ w_ws, const float* __restrict__ e_ws, const float* __restrict__ ad_ws,
    const float* __restrict__ fW, const float* __restrict__ fb,
    const float* __restrict__ pW, const float* __restrict__ pb,
    float* __restrict__ p_out, float* __restrict__ Mv)
{
    __shared__ float s_s[SLEN * DIM];     // rp-final overlay
    __shared__ float e_s[SLEN * DIM];     // e during scan; k tile for the head after
    __shared__ float a_s[SLEN * DIM];
    __shared__ float w_s[SLEN * 56];
    __shared__ float rp_s[2][4][DIM];
    __shared__ int   idxs[32];

    const int bid = blockIdx.x;
    const int b = bid & 63, seg = bid >> 6;
    const int t0 = seg * SLEN;
    const int tid = threadIdx.x;
    const int lane = tid & 63, wv = tid >> 6;

    if (tid < SLEN) idxs[tid] = q[b * NN + t0 + tid];
    for (int k = tid; k < SLEN * 56; k += 256) {
        int row = k / 56, slot = k - row * 56;
        int hh = slot / 28, j = slot - hh * 28;
        w_s[k] = (j < SLEN) ? w_ws[(size_t)(b * NN + t0 + row) * MSZ + hh * SLEN + j] : 0.f;
    }
    for (int k = tid; k < SLEN * DIM; k += 256) {
        int row = k >> 7, c = k & 127;
        size_t g = (size_t)(b * NN + t0 + row) * DIM + c;
        e_s[k] = e_ws[g];
        a_s[k] = ad_ws[g];
    }
    __syncthreads();

    const int hl = lane >> 5, dg = lane & 31, d0 = dg * 4;
    const int p0 = (wv == 0) ? 0 : 7 + 6 * (wv - 1);
    const int np = (wv == 0) ? 7 : 6;

    f4 M4[7];
    #pragma unroll
    for (int j = 0; j < 7; ++j) {
        if (j < np) {
            int row = 2 * (p0 + j) + hl;
            M4[j] = *(const f4*)&Mv0[row * DIM + d0];
        }
    }
    for (int s = 0; s < seg; ++s) {
        const float* Abase = Aseg + (size_t)(b * K1SEG + s) * (MSZ * DIM);
        const float* Bbase = Bseg + (size_t)(b * K1SEG + s) * (MSZ * DIM);
        #pragma unroll
        for (int j = 0; j < 7; ++j) {
            if (j < np) {
                int row = 2 * (p0 + j) + hl;
                f4 A4 = *(const f4*)&Abase[row * DIM + d0];
                f4 B4 = *(const f4*)&Bbase[row * DIM + d0];
                M4[j] = A4 * M4[j] + B4;
            }
        }
    }

    float* MvB = Mv + (size_t)b * (NN + 1) * MSZ * DIM;
    if (seg == 0) {
        #pragma unroll
        for (int j = 0; j < 7; ++j) {
            if (j < np) {
                int row = 2 * (p0 + j) + hl;
                __builtin_nontemporal_store(M4[j], (f4*)&MvB[row * DIM + d0]);
            }
        }
    }
    float* outT = MvB + (size_t)(t0 + 1) * MSZ * DIM;

    for (int tc = 0; tc < SLEN; ++tc) {
        f4 e4 = *(const f4*)&e_s[tc * DIM + d0];
        f4 a4 = *(const f4*)&a_s[tc * DIM + d0];
        float* o = outT + (size_t)tc * MSZ * DIM;
        f4 pr4 = f4{0,0,0,0};
        #pragma unroll
        for (int j = 0; j < 7; ++j) {
            if (j < np) {
                int row = 2 * (p0 + j) + hl;
                float wj = w_s[tc * 56 + wslot(row)];          // LDS broadcast
                pr4 += wj * M4[j];                              // read pre-update
                f4 t1 = a4 - M4[j] * e4;
                M4[j] += wj * t1;                               // M + w*(a - M*e)
                __builtin_nontemporal_store(M4[j], (f4*)&o[row * DIM + d0]);
            }
        }
        pr4.x += __shfl_xor(pr4.x, 32, 64);
        pr4.y += __shfl_xor(pr4.y, 32, 64);
        pr4.z += __shfl_xor(pr4.z, 32, 64);
        pr4.w += __shfl_xor(pr4.w, 32, 64);
        if (lane < 32) *(f4*)&rp_s[tc & 1][wv][d0] = pr4;
        // raw barrier: LDS ordering only — Mv stores stay in flight (no vmcnt drain)
        asm volatile("s_waitcnt lgkmcnt(0)" ::: "memory");
        __builtin_amdgcn_sched_barrier(0);
        __builtin_amdgcn_s_barrier();
        if (wv == (tc & 3) && lane < 32) {                     // summer wave
            f4 s0 = *(const f4*)&rp_s[tc & 1][0][d0];
            f4 s1 = *(const f4*)&rp_s[tc & 1][1][d0];
            f4 s2 = *(const f4*)&rp_s[tc & 1][2][d0];
            f4 s3 = *(const f4*)&rp_s[tc & 1][3][d0];
            *(f4*)&s_s[tc * DIM + d0] = (s0 + s1) + (s2 + s3); // rp-final overlay
        }
    }
    asm volatile("s_waitcnt lgkmcnt(0)" ::: "memory");
    __builtin_amdgcn_sched_barrier(0);
    __builtin_amdgcn_s_barrier();

    // restage k tile into e_s (e no longer needed); head doesn't touch Mv stream
    for (int k = tid; k < SLEN * DIM; k += 256)
        e_s[k] = Kemb[(size_t)idxs[k >> 7] * DIM + (k & 127)];
    asm volatile("s_waitcnt lgkmcnt(0)" ::: "memory");
    __builtin_amdgcn_sched_barrier(0);
    __builtin_amdgcn_s_barrier();

    // head: f = tanh([rp,k]@fW^T+fb); p = sigmoid(f@pW+pb)
    {
        const int c0 = (tid & 31) * 4;
        const int pg = tid >> 5;
        const int npos = (pg == 0) ? 4 : 3;
        const f4* fW4 = (const f4*)fW;

        f4 acc[4][4];
        #pragma unroll
        for (int pi = 0; pi < 4; ++pi)
            #pragma unroll
            for (int j = 0; j < 4; ++j) acc[pi][j] = f4{0,0,0,0};

        for (int i4 = 0; i4 < 64; ++i4) {
            f4 fw0 = fW4[(c0 + 0) * 64 + i4];
            f4 fw1 = fW4[(c0 + 1) * 64 + i4];
            f4 fw2 = fW4[(c0 + 2) * 64 + i4];
            f4 fw3 = fW4[(c0 + 3) * 64 + i4];
            #pragma unroll
            for (int pi = 0; pi < 4; ++pi) {
                if (pi < npos) {
                    int pos = pg + 8 * pi;
                    f4 cat = (i4 < 32) ? *(const f4*)&s_s[pos * DIM + i4 * 4]
                                       : *(const f4*)&e_s[pos * DIM + (i4 - 32) * 4];
                    acc[pi][0] += cat * fw0;
                    acc[pi][1] += cat * fw1;
                    acc[pi][2] += cat * fw2;
                    acc[pi][3] += cat * fw3;
                }
            }
        }
        const f4 fb4 = *(const f4*)&fb[c0];
        const f4 pw4 = *(const f4*)&pW[c0];
        const float pbv = pb[0];
        #pragma unroll
        for (int pi = 0; pi < 4; ++pi) {
            if (pi < npos) {
                int pos = pg + 8 * pi;
                float s = tanhf(hadd(acc[pi][0]) + fb4.x) * pw4.x
                        + tanhf(hadd(acc[pi][1]) + fb4.y) * pw4.y
                        + tanhf(hadd(acc[pi][2]) + fb4.z) * pw4.z
                        + tanhf(hadd(acc[pi][3]) + fb4.w) * pw4.w;
                #pragma unroll
                for (int off = 16; off >= 1; off >>= 1)
                    s += __shfl_xor(s, off, 64);               // width-32 tree (uniform pg per half)
                if (dg == 0)
                    p_out[b * NN + t0 + pos] = 1.f / (1.f + __expf(-(s + pbv)));
            }
        }
    }
}

extern "C" void kernel_launch(void* const* d_in, const int* in_sizes, int n_in,
                              void* d_out, int out_size, void* d_ws, size_t ws_size,
                              hipStream_t stream) {
    const int*   q     = (const int*)d_in[0];
    const int*   r     = (const int*)d_in[1];
    const int*   a     = (const int*)d_in[2];
    const float* Kemb  = (const float*)d_in[3];
    const float* Vemb  = (const float*)d_in[4];
    const float* VAemb = (const float*)d_in[5];
    const float* Mk    = (const float*)d_in[6];
    const float* Mv0   = (const float*)d_in[7];
    const float* fW    = (const float*)d_in[8];
    const float* fb    = (const float*)d_in[9];
    const float* pW    = (const float*)d_in[10];
    const float* pb    = (const float*)d_in[11];
    const float* eW    = (const float*)d_in[12];
    const float* eb    = (const float*)d_in[13];
    const float* aW    = (const float*)d_in[14];
    const float* ab    = (const float*)d_in[15];

    float* p_out = (float*)d_out;
    float* Mv    = p_out + BB * NN;

    float* ws    = (float*)d_ws;
    float* w_ws  = ws;                                      // B*N*50
    float* e_ws  = w_ws + (size_t)BB * NN * MSZ;            // B*N*128
    float* ad_ws = e_ws + (size_t)BB * NN * DIM;            // B*N*128
    float* Aseg  = ad_ws + (size_t)BB * NN * DIM;           // B*7*50*128
    float* Bseg  = Aseg + (size_t)BB * K1SEG * MSZ * DIM;   // B*7*50*128

    kernA<<<BB * SEG, 256, 0, stream>>>(q, r, a, Kemb, Vemb, VAemb, Mk,
                                        eW, eb, aW, ab,
                                        w_ws, e_ws, ad_ws, Aseg, Bseg);
    kernB<<<BB * SEG, 256, 0, stream>>>(q, Kemb, Mv0, Aseg, Bseg,
                                        w_ws, e_ws, ad_ws,
                                        fW, fb, pW, pb, p_out, Mv);
}

// Round 10
// 156.247 us; speedup vs baseline: 1.3240x; 1.3240x over previous
//
#include <hip/hip_runtime.h>
#include <math.h>

#define NUM_Q_ 10000
#define NUM_A_ 10000
#define DIM 128
#define MSZ 50
#define BB 64
#define NN 200
#define SEG 8
#define SLEN 25
#define RPOS 8

typedef float f4 __attribute__((ext_vector_type(4)));

__device__ __forceinline__ float hadd(f4 v) { return (v.x + v.y) + (v.z + v.w); }
// m -> slot in [25][56] padded w layout (halves at 0 and 28; 25 used + 3 zero pad)
__device__ __forceinline__ int wslot(int m) { return m + (m >= 25 ? 3 : 0); }

// ============ kernA (proven, trimmed): gather + GEMVs + softmax -> w/e/ad ============
// grid 512: bid = seg*64 + b (b -> XCD affinity). 256 threads (4 waves).
__global__ __launch_bounds__(256) void kernA(
    const int* __restrict__ q, const int* __restrict__ r, const int* __restrict__ a,
    const float* __restrict__ Kemb, const float* __restrict__ Vemb, const float* __restrict__ VAemb,
    const float* __restrict__ Mk, const float* __restrict__ eW, const float* __restrict__ eb,
    const float* __restrict__ aW, const float* __restrict__ ab,
    float* __restrict__ w_ws, float* __restrict__ e_ws, float* __restrict__ ad_ws)
{
    __shared__ float s_s[SLEN * DIM];
    __shared__ float s_k[SLEN * DIM];
    __shared__ float w_s[SLEN * 56];
    __shared__ int   idxs[96];

    const int bid = blockIdx.x;
    const int b = bid & 63, seg = bid >> 6;
    const int t0 = seg * SLEN;
    const int tid = threadIdx.x;
    const int lane = tid & 63, wv = tid >> 6;

    if (tid < SLEN) {
        int pos = b * NN + t0 + tid;
        int qi = q[pos], ri = r[pos], ai = a[pos];
        idxs[tid]      = qi;
        idxs[32 + tid] = qi + NUM_Q_ * ri;
        idxs[64 + tid] = ai + NUM_A_ * ri;
    }
    for (int k = tid; k < SLEN * 56; k += 256) w_s[k] = 0.f;
    __syncthreads();

    for (int k = tid; k < SLEN * DIM; k += 256) {
        int pl = k >> 7, dc = k & 127;
        s_k[k] = Kemb[(size_t)idxs[pl] * DIM + dc];
        s_s[k] = Vemb[(size_t)idxs[32 + pl] * DIM + dc]
               + VAemb[(size_t)idxs[64 + pl] * DIM + dc];
    }
    __syncthreads();

    {
        const int pw0 = (wv == 0) ? 0 : 7 + 6 * (wv - 1);   // 0,7,13,19
        const int npw = (wv == 0) ? 7 : 6;
        f4 ac0[7], ac1[7], ac2[7], ac3[7], acl[7];
        #pragma unroll
        for (int p = 0; p < 7; ++p) {
            ac0[p] = f4{0,0,0,0}; ac1[p] = f4{0,0,0,0}; ac2[p] = f4{0,0,0,0};
            ac3[p] = f4{0,0,0,0}; acl[p] = f4{0,0,0,0};
        }
        const f4* W0 = (const f4*)(eW + (size_t)lane * DIM);
        const f4* W1 = (const f4*)(eW + (size_t)(lane + 64) * DIM);
        const f4* W2 = (const f4*)(aW + (size_t)lane * DIM);
        const f4* W3 = (const f4*)(aW + (size_t)(lane + 64) * DIM);
        const f4* WM = (const f4*)(Mk + (size_t)(lane < MSZ ? lane : 0) * DIM);

        for (int i4 = 0; i4 < 32; ++i4) {
            f4 w0 = W0[i4], w1 = W1[i4], w2 = W2[i4], w3 = W3[i4], wm = WM[i4];
            #pragma unroll
            for (int p = 0; p < 7; ++p) {
                if (p < npw) {
                    int pos = pw0 + p;
                    f4 s4 = *(const f4*)&s_s[pos * DIM + i4 * 4];
                    f4 k4 = *(const f4*)&s_k[pos * DIM + i4 * 4];
                    ac0[p] += w0 * s4;
                    ac1[p] += w1 * s4;
                    ac2[p] += w2 * s4;
                    ac3[p] += w3 * s4;
                    acl[p] += wm * k4;
                }
            }
        }
        const float eb0 = eb[lane], eb1 = eb[lane + 64];
        const float ab0 = ab[lane], ab1 = ab[lane + 64];
        #pragma unroll
        for (int p = 0; p < 7; ++p) {
            if (p < npw) {
                int pos = pw0 + p;
                size_t g = (size_t)(b * NN + t0 + pos) * DIM;
                e_ws[g + lane]      = 1.f / (1.f + __expf(-(hadd(ac0[p]) + eb0)));
                e_ws[g + lane + 64] = 1.f / (1.f + __expf(-(hadd(ac1[p]) + eb1)));
                ad_ws[g + lane]      = tanhf(hadd(ac2[p]) + ab0);
                ad_ws[g + lane + 64] = tanhf(hadd(ac3[p]) + ab1);
                if (lane < MSZ) w_s[pos * 56 + wslot(lane)] = hadd(acl[p]);
            }
        }
    }
    __syncthreads();

    if (tid < SLEN) {   // softmax over m
        float mx = -1e30f;
        #pragma unroll
        for (int m = 0; m < MSZ; ++m) mx = fmaxf(mx, w_s[tid * 56 + wslot(m)]);
        float sm = 0.f;
        float ex[MSZ];
        #pragma unroll
        for (int m = 0; m < MSZ; ++m) {
            ex[m] = __expf(w_s[tid * 56 + wslot(m)] - mx);
            sm += ex[m];
        }
        float inv = 1.f / sm;
        size_t g = (size_t)(b * NN + t0 + tid) * MSZ;
        #pragma unroll
        for (int m = 0; m < MSZ; ++m)
            w_ws[g + m] = ex[m] * inv;
    }
}

// ============ kernScan: unsegmented 200-step scan; 256 blocks (b, d-quarter) ============
// Thread (mg = tid>>5 in 0..7, d = tid&31) owns m = mg+8j (j<7, m<50) at column dq*32+d.
// Per step: LDS broadcasts + register update + coalesced 128B-row Mv stores; rp via
// 1 shuffle + lgkm-only barrier (Mv stores never drained mid-loop).
__global__ __launch_bounds__(256, 1) void kernScan(
    const float* __restrict__ Mv0,
    const float* __restrict__ w_ws, const float* __restrict__ e_ws, const float* __restrict__ ad_ws,
    float* __restrict__ rp, float* __restrict__ Mv)
{
    __shared__ float w_s[NN * MSZ];     // 40 KB
    __shared__ float e_s[NN * 32];      // 25.6 KB
    __shared__ float a_s[NN * 32];      // 25.6 KB
    __shared__ float rp_s[2][4][32];

    const int bid = blockIdx.x;         // bid = dq*64 + b  -> xcd = b%8 (same as kernA/C)
    const int b = bid & 63, dq = bid >> 6;
    const int tid = threadIdx.x;
    const int lane = tid & 63, wv = tid >> 6;
    const int mg = tid >> 5, d = tid & 31;
    const int NST = (mg < 2) ? 7 : 6;   // wave-uniform per 32-lane half
    const int dg = dq * 32 + d;

    // stage w (full) + e/a (d-quarter slices)
    const float* wb = w_ws + (size_t)b * NN * MSZ;
    for (int k = tid; k < NN * MSZ; k += 256) w_s[k] = wb[k];
    for (int k = tid; k < NN * 32; k += 256) {
        int t = k >> 5, c = k & 31;
        size_t g = (size_t)(b * NN + t) * DIM + dq * 32 + c;
        e_s[k] = e_ws[g];
        a_s[k] = ad_ws[g];
    }
    __syncthreads();

    float M[7];
    #pragma unroll
    for (int j = 0; j < 7; ++j)
        M[j] = (j < NST) ? Mv0[(mg + 8 * j) * DIM + dg] : 0.f;

    float* MvB = Mv + (size_t)b * (NN + 1) * MSZ * DIM;
    #pragma unroll
    for (int j = 0; j < 7; ++j)
        if (j < NST) __builtin_nontemporal_store(M[j], &MvB[(mg + 8 * j) * DIM + dg]);

    float* outT = MvB + MSZ * DIM;
    float* rpo = rp + (size_t)b * NN * DIM + dq * 32;

    for (int t = 0; t < NN; ++t) {
        float ev = e_s[t * 32 + d], av = a_s[t * 32 + d];
        const float* wrow = w_s + t * MSZ;
        float* o = outT + (size_t)t * MSZ * DIM;
        float pr = 0.f;
        #pragma unroll
        for (int j = 0; j < 7; ++j) {
            if (j < NST) {
                float wj = wrow[mg + 8 * j];                   // LDS broadcast per 32-group
                pr = fmaf(wj, M[j], pr);                       // read pre-update memory
                M[j] = fmaf(wj, fmaf(-M[j], ev, av), M[j]);    // M + w*(a - M*e)
                __builtin_nontemporal_store(M[j], &o[(mg + 8 * j) * DIM + dg]);
            }
        }
        pr += __shfl_xor(pr, 32, 64);                          // sum wave's two mg groups
        if (lane < 32) rp_s[t & 1][wv][lane] = pr;
        // lgkm-only barrier: LDS ordering, Mv stores stay in flight
        asm volatile("s_waitcnt lgkmcnt(0)" ::: "memory");
        __builtin_amdgcn_sched_barrier(0);
        __builtin_amdgcn_s_barrier();
        if (wv == (t & 3) && lane < 32) {                      // rotating summer wave
            float s = rp_s[t & 1][0][lane] + rp_s[t & 1][1][lane]
                    + rp_s[t & 1][2][lane] + rp_s[t & 1][3][lane];
            __builtin_nontemporal_store(s, &rpo[(size_t)t * DIM + lane]);
        }
    }
}

// ============ kernC (proven): f = tanh([reads,k]@fW^T+fb), p = sigmoid(f@pW+pb) ============
__global__ __launch_bounds__(128) void kernC(
    const int* __restrict__ q, const float* __restrict__ Kemb,
    const float* __restrict__ rp,
    const float* __restrict__ fW, const float* __restrict__ fb,
    const float* __restrict__ pW, const float* __restrict__ pb,
    float* __restrict__ p_out)
{
    const int bid = blockIdx.x;
    const int b = bid & 63, grp = bid >> 6;
    const int tid = threadIdx.x;
    const int pos0 = b * NN + grp * RPOS;
    __shared__ float s_cat[RPOS][2 * DIM];
    __shared__ float part[2][RPOS];

    #pragma unroll
    for (int p = 0; p < RPOS; ++p) {
        int pos = pos0 + p;
        s_cat[p][tid] = rp[(size_t)pos * DIM + tid];
        s_cat[p][DIM + tid] = Kemb[(size_t)q[pos] * DIM + tid];
    }
    __syncthreads();

    const f4* fWr = (const f4*)(fW + (size_t)tid * 2 * DIM);
    f4 acc4[RPOS];
    #pragma unroll
    for (int p = 0; p < RPOS; ++p) acc4[p] = f4{0,0,0,0};

    for (int i4 = 0; i4 < (2 * DIM) / 4; ++i4) {
        f4 wf = fWr[i4];
        #pragma unroll
        for (int p = 0; p < RPOS; ++p)
            acc4[p] += ((const f4*)s_cat[p])[i4] * wf;
    }

    float fbv = fb[tid], pwv = pW[tid];
    const int wv = tid >> 6, ln = tid & 63;
    #pragma unroll
    for (int p = 0; p < RPOS; ++p) {
        float v = tanhf(hadd(acc4[p]) + fbv) * pwv;
        #pragma unroll
        for (int off = 32; off >= 1; off >>= 1)
            v += __shfl_xor(v, off, 64);
        if (ln == 0) part[wv][p] = v;
    }
    __syncthreads();
    if (tid < RPOS) {
        float pv = part[0][tid] + part[1][tid] + pb[0];
        p_out[pos0 + tid] = 1.f / (1.f + __expf(-pv));
    }
}

extern "C" void kernel_launch(void* const* d_in, const int* in_sizes, int n_in,
                              void* d_out, int out_size, void* d_ws, size_t ws_size,
                              hipStream_t stream) {
    const int*   q     = (const int*)d_in[0];
    const int*   r     = (const int*)d_in[1];
    const int*   a     = (const int*)d_in[2];
    const float* Kemb  = (const float*)d_in[3];
    const float* Vemb  = (const float*)d_in[4];
    const float* VAemb = (const float*)d_in[5];
    const float* Mk    = (const float*)d_in[6];
    const float* Mv0   = (const float*)d_in[7];
    const float* fW    = (const float*)d_in[8];
    const float* fb    = (const float*)d_in[9];
    const float* pW    = (const float*)d_in[10];
    const float* pb    = (const float*)d_in[11];
    const float* eW    = (const float*)d_in[12];
    const float* eb    = (const float*)d_in[13];
    const float* aW    = (const float*)d_in[14];
    const float* ab    = (const float*)d_in[15];

    float* p_out = (float*)d_out;
    float* Mv    = p_out + BB * NN;

    float* ws    = (float*)d_ws;
    float* w_ws  = ws;                                  // B*N*50
    float* e_ws  = w_ws + (size_t)BB * NN * MSZ;        // B*N*128
    float* ad_ws = e_ws + (size_t)BB * NN * DIM;        // B*N*128
    float* rp    = ad_ws + (size_t)BB * NN * DIM;       // B*N*128

    kernA<<<BB * SEG, 256, 0, stream>>>(q, r, a, Kemb, Vemb, VAemb, Mk,
                                        eW, eb, aW, ab, w_ws, e_ws, ad_ws);
    kernScan<<<BB * 4, 256, 0, stream>>>(Mv0, w_ws, e_ws, ad_ws, rp, Mv);
    kernC<<<BB * NN / RPOS, 128, 0, stream>>>(q, Kemb, rp, fW, fb, pW, pb, p_out);
}